// Round 1
// baseline (185.218 us; speedup 1.0000x reference)
//
#include <hip/hip_runtime.h>
#include <cstdint>

typedef short bf16x8 __attribute__((ext_vector_type(8)));
typedef float f32x4 __attribute__((ext_vector_type(4)));

__device__ __forceinline__ unsigned short f2bf(float f) {
  unsigned u = __builtin_bit_cast(unsigned, f);
  u += 0x7fffu + ((u >> 16) & 1u);   // RNE
  return (unsigned short)(u >> 16);
}
__device__ __forceinline__ float bf2f(unsigned short h) {
  unsigned u = ((unsigned)h) << 16;
  return __builtin_bit_cast(float, u);
}
__device__ __forceinline__ float fast_tanh(float x) {
  // tanh(x) = 1 - 2/(exp2(2*log2e*x)+1); exact at +/-inf, |err| ~1e-6
  float e = __builtin_amdgcn_exp2f(x * 2.885390081777927f);
  return 1.0f - 2.0f * __builtin_amdgcn_rcpf(e + 1.0f);
}

// ---------------------------------------------------------------------------
// Stage 1: ConvT3d(1024->8, k4, s4) + b1 + tanh.  stride==k => per-cell GEMM:
//   per bt: C[m=ipos(64)][n=co*64+kpos(512)] = sum_ci x[bt][ci][ipos]*w1[ci][n]
// Output h1[bt][z][y][x][co] fp32 (channel-last for stage-2 staging), in d_ws.
// Block = (bt, co): M=64 x N=64 tile, K=1024 in 32-wide LDS tiles, bf16 MFMA.
// ---------------------------------------------------------------------------
__global__ __launch_bounds__(256) void k_stage1(
    const float* __restrict__ x, const float* __restrict__ w1,
    const float* __restrict__ b1, float* __restrict__ h1) {
  __shared__ unsigned short As[32 * 74];  // [kk 32][m 64 pad->74] bf16
  __shared__ unsigned short Bs[32 * 74];  // [kk 32][n 64 pad->74] bf16
  const int tid = threadIdx.x;
  const int bt = blockIdx.x >> 3;
  const int co = blockIdx.x & 7;
  const int w = tid >> 6;
  const int lane = tid & 63;
  const int lm = lane & 15;
  const int q = lane >> 4;

  f32x4 acc[4];
#pragma unroll
  for (int i = 0; i < 4; ++i) acc[i] = (f32x4){0.f, 0.f, 0.f, 0.f};

  const float* gA = x + (bt << 16);      // x[bt][ci][ipos], 1024*64
  const float* gB = w1 + (co << 6);      // w1[ci][512], n0 = co*64
  const int kk = tid >> 3;
  const int m0h = (tid & 7) << 2;        // dword offset in LDS row

  for (int k0 = 0; k0 < 1024; k0 += 32) {
    {  // A tile: contiguous 2048 floats = x[bt][k0..k0+31][0..63]
      const float* p = gA + (k0 << 6) + (tid << 3);
      float4 f0 = *(const float4*)p;
      float4 f1 = *(const float4*)(p + 4);
      unsigned* dst = (unsigned*)As + kk * 37 + m0h;
      dst[0] = f2bf(f0.x) | ((unsigned)f2bf(f0.y) << 16);
      dst[1] = f2bf(f0.z) | ((unsigned)f2bf(f0.w) << 16);
      dst[2] = f2bf(f1.x) | ((unsigned)f2bf(f1.y) << 16);
      dst[3] = f2bf(f1.z) | ((unsigned)f2bf(f1.w) << 16);
    }
    {  // B tile: w1 rows k0..k0+31 (pitch 512), 64 cols at n0
      const float* p = gB + (k0 + kk) * 512 + ((tid & 7) << 3);
      float4 f0 = *(const float4*)p;
      float4 f1 = *(const float4*)(p + 4);
      unsigned* dst = (unsigned*)Bs + kk * 37 + m0h;
      dst[0] = f2bf(f0.x) | ((unsigned)f2bf(f0.y) << 16);
      dst[1] = f2bf(f0.z) | ((unsigned)f2bf(f0.w) << 16);
      dst[2] = f2bf(f1.x) | ((unsigned)f2bf(f1.y) << 16);
      dst[3] = f2bf(f1.z) | ((unsigned)f2bf(f1.w) << 16);
    }
    __syncthreads();
    union { bf16x8 v; unsigned short u[8]; } a;
#pragma unroll
    for (int j = 0; j < 8; ++j) a.u[j] = As[(q * 8 + j) * 74 + (w << 4) + lm];
#pragma unroll
    for (int nf = 0; nf < 4; ++nf) {
      union { bf16x8 v; unsigned short u[8]; } bfr;
#pragma unroll
      for (int j = 0; j < 8; ++j) bfr.u[j] = Bs[(q * 8 + j) * 74 + (nf << 4) + lm];
      acc[nf] = __builtin_amdgcn_mfma_f32_16x16x32_bf16(a.v, bfr.v, acc[nf], 0, 0, 0);
    }
    __syncthreads();
  }
  const float bias = b1[co];
#pragma unroll
  for (int nf = 0; nf < 4; ++nf) {
#pragma unroll
    for (int r = 0; r < 4; ++r) {
      int m = (w << 4) + (q << 2) + r;  // ipos
      int n = (nf << 4) + lm;           // kpos
      float v = fast_tanh(acc[nf][r] + bias);
      int iz = m >> 4, iy = (m >> 2) & 3, ix = m & 3;
      int kz = n >> 4, ky = (n >> 2) & 3, kx = n & 3;
      int z = (iz << 2) + kz, y = (iy << 2) + ky, xx = (ix << 2) + kx;
      h1[(((bt << 12) + (z << 8) + (y << 4) + xx) << 3) + co] = v;
    }
  }
}

// ---------------------------------------------------------------------------
// Fused stage 2+3: h2 = tanh(ConvT3d(8->8,k4,s4)(h1)+b2) kept as a bf16 LDS
// window; out = Conv3d(8->4,k4,s2,p1)(h2)+b3.
// Block: out tile (z8, y16, x8) for one bt; window (wz18, wy34, wx18 pad20).
// 8 passes over ci_out (cio); thread = (2x,2y,1z) x 4co = 16 accumulators.
// ---------------------------------------------------------------------------
__global__ __launch_bounds__(256) void k_stage23(
    const float* __restrict__ h1, const float* __restrict__ w2,
    const float* __restrict__ b2, const float* __restrict__ w3,
    const float* __restrict__ b3, float* __restrict__ out) {
  __shared__ unsigned short win[18 * 34 * 20];  // [wz][wy][wx pad20] bf16
  __shared__ float h1s[6 * 10 * 6 * 8];         // [uz][uy][ux][ci] fp32
  __shared__ float w2s[8 * 64 * 8];             // [cio][kpos][ci] fp32
  __shared__ unsigned short w3p[2048];          // [cio][kd][kh][kw][co] bf16

  const int tid = threadIdx.x;
  const int bid = blockIdx.x;
  const int bt = bid >> 5;
  const int tile = bid & 31;
  const int tz = tile >> 3, ty = (tile >> 2) & 1, tx = tile & 3;
  const int Z0 = tz << 3, Y0 = ty << 4, X0 = tx << 3;
  const int Qz0 = (Z0 << 1) - 1, Qy0 = (Y0 << 1) - 1, Qx0 = (X0 << 1) - 1;
  const int Uz0 = (tz << 2) - 1, Uy0 = (ty << 3) - 1, Ux0 = (tx << 2) - 1;

  // ---- one-time staging: h1 halo, w2 (transposed), w3 (packed bf16)
  for (int l = tid; l < 2880; l += 256) {
    int ci = l & 7;
    int sp = l >> 3;
    int ux = sp % 6;
    int r = sp / 6;
    int uy = r % 10;
    int uz = r / 10;
    int gz = Uz0 + uz, gy = Uy0 + uy, gx = Ux0 + ux;
    float v = 0.f;
    if ((unsigned)gz < 16u && (unsigned)gy < 16u && (unsigned)gx < 16u)
      v = h1[(((bt << 12) + (gz << 8) + (gy << 4) + gx) << 3) + ci];
    h1s[l] = v;
  }
  for (int l = tid; l < 4096; l += 256) {
    int ci = l & 7;
    int r = l >> 3;
    int kpos = r & 63;
    int cio = r >> 6;
    w2s[(((cio << 6) + kpos) << 3) + ci] = w2[(((ci << 3) + cio) << 6) + kpos];
  }
  for (int l = tid; l < 2048; l += 256) {
    int co = l & 3, kw = (l >> 2) & 3, kh = (l >> 4) & 3, kd = (l >> 6) & 3,
        cio = l >> 8;
    w3p[l] = f2bf(w3[(((co << 3) + cio) << 6) + (kd << 4) + (kh << 2) + kw]);
  }

  float acc[4][2][2];
#pragma unroll
  for (int a = 0; a < 4; ++a)
#pragma unroll
    for (int j = 0; j < 2; ++j)
#pragma unroll
      for (int i = 0; i < 2; ++i) acc[a][j][i] = 0.f;

  const int xq = tid & 3, yq = (tid >> 2) & 7, z0 = tid >> 5;

  for (int cio = 0; cio < 8; ++cio) {
    __syncthreads();  // prev pass conv3 done reading win (covers init staging)
    const float b2c = b2[cio];
    // ---- fill window (deconv2 + bias + tanh), one cio channel
    for (int col = tid; col < 612; col += 256) {  // 612 = 18*34 (wz,wy)
      int wz = col / 34;
      int wy = col - wz * 34;
      int qz = Qz0 + wz, qy = Qy0 + wy;
      unsigned short* wrow = win + (wz * 34 + wy) * 20;
      if ((unsigned)qz < 64u && (unsigned)qy < 64u) {
        int kz = qz & 3, ky = qy & 3;
        int uzp = (qz >> 2) - Uz0, uyp = (qy >> 2) - Uy0;
        const float* w2b = w2s + (((cio << 6) + (kz << 4) + (ky << 2)) << 3);
        f32x4 w2v[4][2];
#pragma unroll
        for (int kx = 0; kx < 4; ++kx) {
          w2v[kx][0] = *(const f32x4*)(w2b + (kx << 3));
          w2v[kx][1] = *(const f32x4*)(w2b + (kx << 3) + 4);
        }
        const float* h1b = h1s + (((uzp * 10 + uyp) * 6) << 3);
        float vals[18];
        {  // wx=0: qx=Qx0 (kx=3, uxp=0); invalid only when tx==0 (qx=-1)
          float v = 0.f;
          if (Qx0 >= 0) {
            f32x4 h0 = *(const f32x4*)h1b;
            f32x4 h4 = *(const f32x4*)(h1b + 4);
            f32x4 wa = w2v[3][0], wb = w2v[3][1];
            float d = h0.x * wa.x + h0.y * wa.y + h0.z * wa.z + h0.w * wa.w +
                      h4.x * wb.x + h4.y * wb.y + h4.z * wb.z + h4.w * wb.w;
            v = fast_tanh(d + b2c);
          }
          vals[0] = v;
        }
#pragma unroll
        for (int c = 0; c < 4; ++c) {  // full cells: wx = 1+4c+kx, uxp=c+1
          const float* hp = h1b + ((c + 1) << 3);
          f32x4 h0 = *(const f32x4*)hp;
          f32x4 h4 = *(const f32x4*)(hp + 4);
#pragma unroll
          for (int kx = 0; kx < 4; ++kx) {
            f32x4 wa = w2v[kx][0], wb = w2v[kx][1];
            float d = h0.x * wa.x + h0.y * wa.y + h0.z * wa.z + h0.w * wa.w +
                      h4.x * wb.x + h4.y * wb.y + h4.z * wb.z + h4.w * wb.w;
            vals[1 + (c << 2) + kx] = fast_tanh(d + b2c);
          }
        }
        {  // wx=17: qx=Qx0+17 (kx=0, uxp=5); invalid only when tx==3 (qx=64)
          float v = 0.f;
          if (Qx0 + 17 < 64) {
            const float* hp = h1b + (5 << 3);
            f32x4 h0 = *(const f32x4*)hp;
            f32x4 h4 = *(const f32x4*)(hp + 4);
            f32x4 wa = w2v[0][0], wb = w2v[0][1];
            float d = h0.x * wa.x + h0.y * wa.y + h0.z * wa.z + h0.w * wa.w +
                      h4.x * wb.x + h4.y * wb.y + h4.z * wb.z + h4.w * wb.w;
            v = fast_tanh(d + b2c);
          }
          vals[17] = v;
        }
#pragma unroll
        for (int wx = 0; wx < 18; ++wx) wrow[wx] = f2bf(vals[wx]);
      } else {
#pragma unroll
        for (int wx = 0; wx < 18; ++wx) wrow[wx] = 0;
      }
    }
    __syncthreads();
    // ---- conv3 accumulation for this cio
#pragma unroll
    for (int kd = 0; kd < 4; ++kd) {
      int wz = (z0 << 1) + kd;
#pragma unroll
      for (int kh = 0; kh < 4; ++kh) {
        const unsigned* w3q =
            (const unsigned*)w3p + ((((cio << 2) + kd) << 2) + kh) * 8;
        float w3f[4][4];  // [kw][co]
#pragma unroll
        for (int p = 0; p < 8; ++p) {
          unsigned d = w3q[p];
          w3f[p >> 1][(p & 1) << 1] = bf2f((unsigned short)(d & 0xffffu));
          w3f[p >> 1][((p & 1) << 1) + 1] = bf2f((unsigned short)(d >> 16));
        }
#pragma unroll
        for (int j = 0; j < 2; ++j) {
          int wy = (((yq << 1) + j) << 1) + kh;
          const unsigned* rq =
              (const unsigned*)(win + (wz * 34 + wy) * 20) + (xq << 1);
          unsigned r0 = rq[0], r1 = rq[1], r2 = rq[2];
          float v[6];
          v[0] = bf2f((unsigned short)(r0 & 0xffffu));
          v[1] = bf2f((unsigned short)(r0 >> 16));
          v[2] = bf2f((unsigned short)(r1 & 0xffffu));
          v[3] = bf2f((unsigned short)(r1 >> 16));
          v[4] = bf2f((unsigned short)(r2 & 0xffffu));
          v[5] = bf2f((unsigned short)(r2 >> 16));
#pragma unroll
          for (int kw = 0; kw < 4; ++kw)
#pragma unroll
            for (int i = 0; i < 2; ++i) {
              float hv = v[(i << 1) + kw];
#pragma unroll
              for (int c4 = 0; c4 < 4; ++c4) acc[c4][j][i] += hv * w3f[kw][c4];
            }
        }
      }
    }
  }
  // ---- epilogue: + b3, store to (B, C, 32,32,32, T) with t innermost
  const int b = bt >> 3, t8 = bt & 7;
  const int z = Z0 + z0;
#pragma unroll
  for (int c4 = 0; c4 < 4; ++c4) {
    float bias = b3[c4];
#pragma unroll
    for (int j = 0; j < 2; ++j) {
      int y = Y0 + (yq << 1) + j;
#pragma unroll
      for (int i = 0; i < 2; ++i) {
        int xx = X0 + (xq << 1) + i;
        out[(((((b << 2) + c4) * 32 + z) * 32 + y) * 32 + xx) << 3 | t8] =
            acc[c4][j][i] + bias;
      }
    }
  }
}

extern "C" void kernel_launch(void* const* d_in, const int* in_sizes, int n_in,
                              void* d_out, int out_size, void* d_ws,
                              size_t ws_size, hipStream_t stream) {
  (void)in_sizes; (void)n_in; (void)out_size; (void)ws_size;
  const float* x = (const float*)d_in[0];
  const float* w1 = (const float*)d_in[1];
  const float* b1 = (const float*)d_in[2];
  const float* w2 = (const float*)d_in[3];
  const float* b2 = (const float*)d_in[4];
  const float* w3 = (const float*)d_in[5];
  const float* b3 = (const float*)d_in[6];
  float* out = (float*)d_out;
  float* h1 = (float*)d_ws;  // 524288 floats (2 MB)

  k_stage1<<<dim3(128), dim3(256), 0, stream>>>(x, w1, b1, h1);
  k_stage23<<<dim3(512), dim3(256), 0, stream>>>(h1, w2, b2, w3, b3, out);
}

// Round 2
// 168.873 us; speedup vs baseline: 1.0968x; 1.0968x over previous
//
#include <hip/hip_runtime.h>
#include <cstdint>

typedef short bf16x8 __attribute__((ext_vector_type(8)));
typedef float f32x4 __attribute__((ext_vector_type(4)));

__device__ __forceinline__ unsigned short f2bf(float f) {
  unsigned u = __builtin_bit_cast(unsigned, f);
  u += 0x7fffu + ((u >> 16) & 1u);   // RNE
  return (unsigned short)(u >> 16);
}
__device__ __forceinline__ float bflo(unsigned u) {
  return __builtin_bit_cast(float, u << 16);
}
__device__ __forceinline__ float bfhi(unsigned u) {
  return __builtin_bit_cast(float, u & 0xffff0000u);
}
__device__ __forceinline__ float fast_tanh(float x) {
  // tanh(x) = 1 - 2/(exp2(2*log2e*x)+1); exact at +/-inf
  float e = __builtin_amdgcn_exp2f(x * 2.885390081777927f);
  return 1.0f - 2.0f * __builtin_amdgcn_rcpf(e + 1.0f);
}

// Packed bf16 pair dot: d = a.lo*b.lo + a.hi*b.hi + c
#if __has_builtin(__builtin_amdgcn_fdot2_f32_bf16)
typedef __bf16 bf16x2 __attribute__((ext_vector_type(2)));
__device__ __forceinline__ float dot2bf(unsigned a, unsigned b, float c) {
  return __builtin_amdgcn_fdot2_f32_bf16(__builtin_bit_cast(bf16x2, a),
                                         __builtin_bit_cast(bf16x2, b), c,
                                         false);
}
#else
__device__ __forceinline__ float dot2bf(unsigned a, unsigned b, float c) {
  c = fmaf(bflo(a), bflo(b), c);
  c = fmaf(bfhi(a), bfhi(b), c);
  return c;
}
#endif

// ---------------------------------------------------------------------------
// Stage 1: ConvT3d(1024->8, k4, s4) + b1 + tanh. stride==k => per-cell GEMM:
//   per bt: C[m=ipos(64)][n=co*64+kpos] = sum_ci x[bt][ci][m]*w1[ci][n]
// LDS tiles stored [row][k] (pitch 40 hw, 16B-aligned rows) so MFMA fragments
// are single ds_read_b128. Staging: coalesced global dwords + uint4 LDS write.
// ---------------------------------------------------------------------------
__global__ __launch_bounds__(256) void k_stage1(
    const float* __restrict__ x, const float* __restrict__ w1,
    const float* __restrict__ b1, float* __restrict__ h1) {
  __shared__ __align__(16) unsigned short As[64 * 40];  // [m][kk0..31 pad40]
  __shared__ __align__(16) unsigned short Bs[64 * 40];  // [n][kk0..31 pad40]
  const int tid = threadIdx.x;
  const int bt = blockIdx.x >> 3;
  const int co = blockIdx.x & 7;
  const int w = tid >> 6;
  const int lane = tid & 63;
  const int lm = lane & 15;
  const int q = lane >> 4;

  f32x4 acc[4];
#pragma unroll
  for (int i = 0; i < 4; ++i) acc[i] = (f32x4){0.f, 0.f, 0.f, 0.f};

  const float* gA = x + (bt << 16);  // x[bt][ci][m], 1024x64
  const float* gB = w1 + (co << 6);  // w1[ci][512], cols co*64..+63
  const int rrow = tid & 63;         // m for A, n-local for B
  const int kgr = tid >> 6;          // 0..3 (k-granule of 8)

  for (int k0 = 0; k0 < 1024; k0 += 32) {
    {  // A stage: lane-coalesced dword loads, transposed packed write
      float va[8];
#pragma unroll
      for (int j = 0; j < 8; ++j)
        va[j] = gA[(k0 + (kgr << 3) + j) << 6 | rrow];
      uint4 p;
      p.x = f2bf(va[0]) | ((unsigned)f2bf(va[1]) << 16);
      p.y = f2bf(va[2]) | ((unsigned)f2bf(va[3]) << 16);
      p.z = f2bf(va[4]) | ((unsigned)f2bf(va[5]) << 16);
      p.w = f2bf(va[6]) | ((unsigned)f2bf(va[7]) << 16);
      *(uint4*)&As[rrow * 40 + (kgr << 3)] = p;
    }
    {  // B stage
      float vb[8];
#pragma unroll
      for (int j = 0; j < 8; ++j)
        vb[j] = gB[(k0 + (kgr << 3) + j) * 512 + rrow];
      uint4 p;
      p.x = f2bf(vb[0]) | ((unsigned)f2bf(vb[1]) << 16);
      p.y = f2bf(vb[2]) | ((unsigned)f2bf(vb[3]) << 16);
      p.z = f2bf(vb[4]) | ((unsigned)f2bf(vb[5]) << 16);
      p.w = f2bf(vb[6]) | ((unsigned)f2bf(vb[7]) << 16);
      *(uint4*)&Bs[rrow * 40 + (kgr << 3)] = p;
    }
    __syncthreads();
    bf16x8 a = *(const bf16x8*)&As[((w << 4) + lm) * 40 + (q << 3)];
#pragma unroll
    for (int nf = 0; nf < 4; ++nf) {
      bf16x8 b = *(const bf16x8*)&Bs[((nf << 4) + lm) * 40 + (q << 3)];
      acc[nf] = __builtin_amdgcn_mfma_f32_16x16x32_bf16(a, b, acc[nf], 0, 0, 0);
    }
    __syncthreads();
  }
  const float bias = b1[co];
#pragma unroll
  for (int nf = 0; nf < 4; ++nf) {
#pragma unroll
    for (int r = 0; r < 4; ++r) {
      int m = (w << 4) + (q << 2) + r;  // ipos
      int n = (nf << 4) + lm;           // kpos
      float v = fast_tanh(acc[nf][r] + bias);
      int iz = m >> 4, iy = (m >> 2) & 3, ix = m & 3;
      int kz = n >> 4, ky = (n >> 2) & 3, kx = n & 3;
      int z = (iz << 2) + kz, y = (iy << 2) + ky, xx = (ix << 2) + kx;
      h1[(((bt << 12) + (z << 8) + (y << 4) + xx) << 3) + co] = v;
    }
  }
}

// ---------------------------------------------------------------------------
// Fused stage 2+3. win = bf16 h2 window, rows of 18 bf16 padded to 24 hw
// (12 dwords, 16B-aligned rows; lane bank-windows tile uniformly).
// Fill math fp32 (h1s/w2s fp32, unchanged quantization surface vs R1).
// Conv3 core: packed-bf16 dot2 on win dwords x kw-paired w3.
// Thread = (xh in {0,1} -> 4-wide x strip, y 0..15, z 0..7) x 4 co = 16 acc.
// ---------------------------------------------------------------------------
__global__ __launch_bounds__(256) void k_stage23(
    const float* __restrict__ h1, const float* __restrict__ w2,
    const float* __restrict__ b2, const float* __restrict__ w3,
    const float* __restrict__ b3, float* __restrict__ out) {
  __shared__ __align__(16) unsigned win_d[18 * 34 * 12];  // dwords (24hw rows)
  __shared__ __align__(16) float h1s[6 * 10 * 6 * 8];     // [uz][uy][ux][ci]
  __shared__ __align__(16) float w2s[8 * 64 * 8];         // [cio][kpos][ci]
  __shared__ __align__(16) unsigned w3p[1024];  // [cio][kd][kh][pair][c4]

  const int tid = threadIdx.x;
  const int bid = blockIdx.x;
  const int bt = bid >> 5;
  const int tile = bid & 31;
  const int tz = tile >> 3, ty = (tile >> 2) & 1, tx = tile & 3;
  const int Z0 = tz << 3, Y0 = ty << 4, X0 = tx << 3;
  const int Qz0 = (Z0 << 1) - 1, Qy0 = (Y0 << 1) - 1, Qx0 = (X0 << 1) - 1;
  const int Uz0 = (tz << 2) - 1, Uy0 = (ty << 3) - 1, Ux0 = (tx << 2) - 1;

  // ---- one-time staging
  for (int l = tid; l < 2880; l += 256) {
    int ci = l & 7;
    int sp = l >> 3;
    int ux = sp % 6;
    int r = sp / 6;
    int uy = r % 10;
    int uz = r / 10;
    int gz = Uz0 + uz, gy = Uy0 + uy, gx = Ux0 + ux;
    float v = 0.f;
    if ((unsigned)gz < 16u && (unsigned)gy < 16u && (unsigned)gx < 16u)
      v = h1[(((bt << 12) + (gz << 8) + (gy << 4) + gx) << 3) + ci];
    h1s[l] = v;
  }
  for (int l = tid; l < 4096; l += 256) {
    int ci = l & 7;
    int r = l >> 3;
    int kpos = r & 63;
    int cio = r >> 6;
    w2s[(((cio << 6) + kpos) << 3) + ci] = w2[(((ci << 3) + cio) << 6) + kpos];
  }
  for (int l = tid; l < 1024; l += 256) {
    // dword l = [cio][kd][kh][pair][c4]
    int c4 = l & 3, pair = (l >> 2) & 1, kh = (l >> 3) & 3, kd = (l >> 5) & 3,
        cio = l >> 7;
    int base = (((c4 << 3) + cio) << 6) + (kd << 4) + (kh << 2) + (pair << 1);
    w3p[l] = (unsigned)f2bf(w3[base]) | ((unsigned)f2bf(w3[base + 1]) << 16);
  }

  float acc[4][4];  // [c4][i]
#pragma unroll
  for (int a = 0; a < 4; ++a)
#pragma unroll
    for (int i = 0; i < 4; ++i) acc[a][i] = 0.f;

  const int xh = tid & 1, yq = (tid >> 1) & 15, zq = tid >> 5;

  for (int cio = 0; cio < 8; ++cio) {
    __syncthreads();  // prev conv done reading win (covers init staging too)
    const float b2c = b2[cio];
    // ---- fill window (deconv2 + bias + tanh), one cio channel
    for (int col = tid; col < 612; col += 256) {  // 612 = 18*34 (wz,wy)
      int wz = col / 34;
      int wy = col - wz * 34;
      unsigned* wrow = win_d + (wz * 34 + wy) * 12;
      int qz = Qz0 + wz, qy = Qy0 + wy;
      if ((unsigned)qz < 64u && (unsigned)qy < 64u) {
        int kz = qz & 3, ky = qy & 3;
        int uzp = (qz >> 2) - Uz0, uyp = (qy >> 2) - Uy0;
        const float* w2b = w2s + (((cio << 6) + (kz << 4) + (ky << 2)) << 3);
        f32x4 w2v[4][2];
#pragma unroll
        for (int kx = 0; kx < 4; ++kx) {
          w2v[kx][0] = *(const f32x4*)(w2b + (kx << 3));
          w2v[kx][1] = *(const f32x4*)(w2b + (kx << 3) + 4);
        }
        const float* h1b = h1s + (((uzp * 10 + uyp) * 6) << 3);
        float vals[18];
        {  // wx=0: kx=3, cell 0; invalid only when tx==0
          float v = 0.f;
          if (Qx0 >= 0) {
            f32x4 h0 = *(const f32x4*)h1b;
            f32x4 h4 = *(const f32x4*)(h1b + 4);
            f32x4 wa = w2v[3][0], wb = w2v[3][1];
            float d = h0.x * wa.x + h0.y * wa.y + h0.z * wa.z + h0.w * wa.w +
                      h4.x * wb.x + h4.y * wb.y + h4.z * wb.z + h4.w * wb.w;
            v = fast_tanh(d + b2c);
          }
          vals[0] = v;
        }
#pragma unroll
        for (int c = 0; c < 4; ++c) {  // full cells: wx = 1+4c+kx
          const float* hp = h1b + ((c + 1) << 3);
          f32x4 h0 = *(const f32x4*)hp;
          f32x4 h4 = *(const f32x4*)(hp + 4);
#pragma unroll
          for (int kx = 0; kx < 4; ++kx) {
            f32x4 wa = w2v[kx][0], wb = w2v[kx][1];
            float d = h0.x * wa.x + h0.y * wa.y + h0.z * wa.z + h0.w * wa.w +
                      h4.x * wb.x + h4.y * wb.y + h4.z * wb.z + h4.w * wb.w;
            vals[1 + (c << 2) + kx] = fast_tanh(d + b2c);
          }
        }
        {  // wx=17: kx=0, cell 5; invalid only when tx==3
          float v = 0.f;
          if (Qx0 + 17 < 64) {
            const float* hp = h1b + (5 << 3);
            f32x4 h0 = *(const f32x4*)hp;
            f32x4 h4 = *(const f32x4*)(hp + 4);
            f32x4 wa = w2v[0][0], wb = w2v[0][1];
            float d = h0.x * wa.x + h0.y * wa.y + h0.z * wa.z + h0.w * wa.w +
                      h4.x * wb.x + h4.y * wb.y + h4.z * wb.z + h4.w * wb.w;
            v = fast_tanh(d + b2c);
          }
          vals[17] = v;
        }
        uint4 s0, s1;
        s0.x = f2bf(vals[0]) | ((unsigned)f2bf(vals[1]) << 16);
        s0.y = f2bf(vals[2]) | ((unsigned)f2bf(vals[3]) << 16);
        s0.z = f2bf(vals[4]) | ((unsigned)f2bf(vals[5]) << 16);
        s0.w = f2bf(vals[6]) | ((unsigned)f2bf(vals[7]) << 16);
        s1.x = f2bf(vals[8]) | ((unsigned)f2bf(vals[9]) << 16);
        s1.y = f2bf(vals[10]) | ((unsigned)f2bf(vals[11]) << 16);
        s1.z = f2bf(vals[12]) | ((unsigned)f2bf(vals[13]) << 16);
        s1.w = f2bf(vals[14]) | ((unsigned)f2bf(vals[15]) << 16);
        unsigned s2 = f2bf(vals[16]) | ((unsigned)f2bf(vals[17]) << 16);
        *(uint4*)wrow = s0;
        *(uint4*)(wrow + 4) = s1;
        wrow[8] = s2;
      } else {
        uint4 zz;
        zz.x = zz.y = zz.z = zz.w = 0u;
        *(uint4*)wrow = zz;
        *(uint4*)(wrow + 4) = zz;
        wrow[8] = 0u;
      }
    }
    __syncthreads();
    // ---- conv3 accumulation for this cio (packed bf16 dot2)
#pragma unroll
    for (int kd = 0; kd < 4; ++kd) {
      int wz = (zq << 1) + kd;
#pragma unroll
      for (int kh = 0; kh < 4; ++kh) {
        int wy = (yq << 1) + kh;
        const unsigned* rowp = win_d + (wz * 34 + wy) * 12 + (xh << 2);
        uint4 rv = *(const uint4*)rowp;
        unsigned r4 = rowp[4];
        unsigned r[5] = {rv.x, rv.y, rv.z, rv.w, r4};
        const uint4* wp =
            (const uint4*)w3p + (((cio << 4) + (kd << 2) + kh) << 1);
        uint4 wAv = wp[0], wBv = wp[1];
        unsigned wA[4] = {wAv.x, wAv.y, wAv.z, wAv.w};
        unsigned wB[4] = {wBv.x, wBv.y, wBv.z, wBv.w};
#pragma unroll
        for (int c4 = 0; c4 < 4; ++c4) {
#pragma unroll
          for (int i = 0; i < 4; ++i) {
            float a0 = dot2bf(r[i], wA[c4], acc[c4][i]);
            acc[c4][i] = dot2bf(r[i + 1], wB[c4], a0);
          }
        }
      }
    }
  }
  // ---- epilogue: + b3, store to (B, C, 32,32,32, T) with t innermost
  const int b = bt >> 3, t8 = bt & 7;
  const int z = Z0 + zq;
  const int y = Y0 + yq;
#pragma unroll
  for (int c4 = 0; c4 < 4; ++c4) {
    float bias = b3[c4];
#pragma unroll
    for (int i = 0; i < 4; ++i) {
      int xx = X0 + (xh << 2) + i;
      out[(((((b << 2) + c4) * 32 + z) * 32 + y) * 32 + xx) << 3 | t8] =
          acc[c4][i] + bias;
    }
  }
}

extern "C" void kernel_launch(void* const* d_in, const int* in_sizes, int n_in,
                              void* d_out, int out_size, void* d_ws,
                              size_t ws_size, hipStream_t stream) {
  (void)in_sizes; (void)n_in; (void)out_size; (void)ws_size;
  const float* x = (const float*)d_in[0];
  const float* w1 = (const float*)d_in[1];
  const float* b1 = (const float*)d_in[2];
  const float* w2 = (const float*)d_in[3];
  const float* b2 = (const float*)d_in[4];
  const float* w3 = (const float*)d_in[5];
  const float* b3 = (const float*)d_in[6];
  float* out = (float*)d_out;
  float* h1 = (float*)d_ws;  // 524288 floats (2 MB)

  k_stage1<<<dim3(128), dim3(256), 0, stream>>>(x, w1, b1, h1);
  k_stage23<<<dim3(512), dim3(256), 0, stream>>>(h1, w2, b2, w3, b3, out);
}